// Round 5
// baseline (14348.302 us; speedup 1.0000x reference)
//
#include <hip/hip_runtime.h>
#include <hip/hip_bf16.h>
#include <cstdint>
#include <cstddef>

#define DEV __device__ __forceinline__

typedef _Float16 h2v __attribute__((ext_vector_type(2)));
typedef unsigned u4v __attribute__((ext_vector_type(4)));

DEV float sigmoidf_(float x) { return 1.0f / (1.0f + __expf(-x)); }
DEV float tanhf_(float x) {
    float e = __expf(2.0f * x);
    return 1.0f - 2.0f / (e + 1.0f);
}
DEV h2v asH2(unsigned x) { union { unsigned u; h2v h; } c; c.u = x; return c.h; }

// Un-sinkable, un-rematerializable 16B load (resident weights).
DEV u4v gload(const void* p) {
    u4v r;
    asm volatile("global_load_dwordx4 %0, %1, off\n\ts_waitcnt vmcnt(0)"
                 : "=v"(r) : "v"(p) : "memory");
    return r;
}

// v_fma_mix_f32: f16(lo/hi of 32b reg) * f16(lo/hi) + f32 -> f32.
// Full-rate VOP3P mix op — replaces v_dot2_f32_f16 which measures ~9cy/issue
// across v15-v19 (quarter-rate). Non-volatile asm: schedulable, DCE-able.
DEV float mixfma_lo(unsigned h, unsigned w, float a) {
    float d;
    asm("v_fma_mix_f32 %0, %1, %2, %3 op_sel_hi:[1,1,0]"
        : "=v"(d) : "v"(h), "v"(w), "v"(a));
    return d;
}
DEV float mixfma_hi(unsigned h, unsigned w, float a) {
    float d;
    asm("v_fma_mix_f32 %0, %1, %2, %3 op_sel:[1,1,0] op_sel_hi:[1,1,0]"
        : "=v"(d) : "v"(h), "v"(w), "v"(a));
    return d;
}

// LDS-only barrier: does NOT drain vmcnt; global prefetch/stores stay in flight.
#define LDS_BARRIER() asm volatile("s_waitcnt lgkmcnt(0)\n\ts_barrier" ::: "memory")

// ---------------------------------------------------------------------------
// Pack 10 matrices (256x64 each) to f16 pairs, split-K layout:
//   dst[m][half][qs][u][w]   (qs = q*4+s: gate q, slice s; w = word 0..3)
// m: 0-2 l1Whh, 3-5 l2Whh, 6-7 Wih12 (l1 layers 1,2), 8-9 l2Wih layers 1,2.
// Quad (half,q,s,u) holds W[gate q][unit u][k = 32*half + 8*s .. +7].
// ---------------------------------------------------------------------------
__global__ __launch_bounds__(256) void pack_w(
    const float* __restrict__ l1Whh, const float* __restrict__ l2Whh,
    const float* __restrict__ Wih12, const float* __restrict__ l2Wih,
    unsigned* __restrict__ wP)
{
    int idx = blockIdx.x * 256 + threadIdx.x;   // 10*8192 = 81920
    int m = idx >> 13;
    int rem = idx & 8191;
    int half = rem >> 12;
    int qs = (rem >> 8) & 15;
    int u = (rem >> 2) & 63;
    int w = rem & 3;
    int q = qs >> 2, s = qs & 3;
    int jp = 16 * half + 4 * s + w;

    const float* W;
    if (m < 3)      W = l1Whh + (size_t)m * 16384;
    else if (m < 6) W = l2Whh + (size_t)(m - 3) * 16384;
    else if (m < 8) W = Wih12 + (size_t)(m - 6) * 16384;
    else            W = l2Wih + (size_t)(m - 7) * 16384;   // layers 1,2

    const float* row = W + (size_t)(q * 64 + u) * 64;
    union { h2v h; unsigned u32; } c;
    c.h = (h2v){(_Float16)row[2 * jp], (_Float16)row[2 * jp + 1]};
    wP[idx] = c.u32;
}

// ---------------------------------------------------------------------------
// Input projection (layer 0 of each stack only): xg[b,t,u*4+q] unit-major.
// ---------------------------------------------------------------------------
__global__ __launch_bounds__(256) void proj_kernel(
    const float* __restrict__ x, const float* __restrict__ Wih,
    const float* __restrict__ bias, const float* __restrict__ gate,
    float* __restrict__ xg, int D, int T)
{
    __shared__ float xS[16 * 64];
    int tb = T / 16;
    int b  = blockIdx.x / tb;
    int t0 = (blockIdx.x % tb) * 16;
    int tid = threadIdx.x;

    int n = 16 * D;
    for (int e = tid; e < n; e += 256) {
        int t = e / D;
        int i = e - t * D;
        float v = x[((size_t)(b * T + t0 + t)) * D + i];
        if (gate) v += gate[b * T + t0 + t];
        xS[t * D + i] = v;
    }
    __syncthreads();

    int g = tid;
    float acc[16];
    float bg = bias[g];
#pragma unroll
    for (int t = 0; t < 16; t++) acc[t] = bg;

    const float* wr = Wih + (size_t)g * D;
    for (int i = 0; i < D; i++) {
        float w = wr[i];
#pragma unroll
        for (int t = 0; t < 16; t++) acc[t] += xS[t * D + i] * w;
    }

    float* og = xg + ((size_t)(b * T + t0)) * 256 + (g & 63) * 4 + (g >> 6);
#pragma unroll
    for (int t = 0; t < 16; t++) og[(size_t)t * 256] = acc[t];
}

// ---------------------------------------------------------------------------
// Chunked 3-layer LSTM scan v20: v18 structure, v_fma_mix_f32 micro-op.
//
// v15-v19 post-mortem: FIVE structures (different waves/SIMD, barriers, ILP,
// register strategies) all measure ~9 cy per v_dot2_f32_f16 issue slot ->
// the dot op itself is quarter-rate-ish on gfx950. v20 keeps v18 (best
// 3-wave host: resident Whh 128 VGPR, Wih chunk-GEMM from LDS once/4 ticks,
// RR=8 epochs, 1 barrier/epoch, parity-buffered hchunk) and swaps every
// fdot2 for TWO v_fma_mix_f32 (full-rate f16xf16+f32): issue cost per tick
// 128x9 -> 256x2 cy for each matrix term. v19's extras (16 accums, hq
// pre-read, GEMM interleave) are REVERTED: they regressed under the real
// (throughput) bottleneck.
// ---------------------------------------------------------------------------
#define RR 8

__global__
__attribute__((amdgpu_flat_work_group_size(192, 192), amdgpu_waves_per_eu(1, 1)))
void scan3_kernel(
    const float* __restrict__ xg, const unsigned* __restrict__ whhP,
    const unsigned* __restrict__ wihP, const float* __restrict__ bvec,
    const float* __restrict__ h0, const float* __restrict__ c0,
    float* __restrict__ Hout, int T)
{
    __shared__ __align__(16) u4v wihS[4096];                 // 64 KB (Wih l1,l2)
    __shared__ __align__(16) _Float16 hchunk[2][2][RR][64];  // 4 KB
    __shared__ __align__(16) _Float16 hself[3][64];

    const int b = blockIdx.x, tid = threadIdx.x;
    const int l = tid >> 6, u = tid & 63;

    // stage Wih (both layers, packed layout) into LDS
    for (int i = tid; i < 4096; i += 192) wihS[i] = ((const u4v*)wihP)[i];

    // resident Whh: whh[g*8+ks] = W[gate g][unit u][k=8*ks..8*ks+7]
    u4v whh[32];
    {
        const u4v* wp = (const u4v*)whhP + (size_t)l * 2048 + u;
#pragma unroll
        for (int g = 0; g < 4; g++)
#pragma unroll
            for (int ks = 0; ks < 8; ks++)
                whh[g * 8 + ks] = gload(wp + (ks >> 2) * 1024 + (g * 4 + (ks & 3)) * 64);
    }

    float cst = c0[l * 128 + b * 64 + u];
    hself[l][u] = (_Float16)h0[l * 128 + b * 64 + u];
    float4 bl = make_float4(0.f, 0.f, 0.f, 0.f);
    if (l > 0) {
        const float* bb = bvec + l * 256;
        bl = make_float4(bb[u], bb[64 + u], bb[128 + u], bb[192 + u]);
    }

    // acc4: L0 = rolling x prefetch (ticks tau..tau+3); L1/L2 = GEMM accums
    const float4* xp = (const float4*)(xg + (size_t)b * T * 256) + u;
    float4 acc4[4];
    if (l == 0) {
#pragma unroll
        for (int k = 0; k < 4; k++) acc4[k] = xp[(size_t)k * 64];
    } else {
#pragma unroll
        for (int k = 0; k < 4; k++) acc4[k] = bl;
    }

    float* houtp = Hout + (size_t)b * T * 64 + u;
    const u4v* hs = (const u4v*)&hself[l][0];
    const u4v* wb = wihS + (size_t)(l > 0 ? l - 1 : 0) * 2048 + u;
    const int lb = (l > 0 ? l - 1 : 0);

    __syncthreads();

// one packed f16-pair MAC: two full-rate mix-FMAs (replaces 1 fdot2)
#define FD(HP, WV, A) { A = mixfma_lo((HP), (WV), A); \
                        A = mixfma_hi((HP), (WV), A); }
#define FD4(HQ, WQ, A) { FD(HQ.x, (WQ).x, A); FD(HQ.y, (WQ).y, A); \
                         FD(HQ.z, (WQ).z, A); FD(HQ.w, (WQ).w, A); }

    // one gate of the chunk-GEMM: stream Wih quad once, hit 4 ticks
#define GEMMG(G, ACCSEL) {                                              \
    u4v wq = wb[(ks >> 2) * 1024 + ((G) * 4 + (ks & 3)) * 64];          \
    FD4(hb0, wq, acc4[0].ACCSEL);                                       \
    FD4(hb1, wq, acc4[1].ACCSEL);                                       \
    FD4(hb2, wq, acc4[2].ACCSEL);                                       \
    FD4(hb3, wq, acc4[3].ACCSEL);                                       \
}

#define GEMMHALF(H) {                                                   \
    acc4[0] = bl; acc4[1] = bl; acc4[2] = bl; acc4[3] = bl;             \
    _Pragma("unroll")                                                   \
    for (int ks = 0; ks < 8; ks++) {                                    \
        u4v hb0 = hbase[((H) * 4 + 0) * 8 + ks];                        \
        u4v hb1 = hbase[((H) * 4 + 1) * 8 + ks];                        \
        u4v hb2 = hbase[((H) * 4 + 2) * 8 + ks];                        \
        u4v hb3 = hbase[((H) * 4 + 3) * 8 + ks];                        \
        GEMMG(0, x) GEMMG(1, y) GEMMG(2, z) GEMMG(3, w)                 \
    }                                                                   \
}

    // one LSTM tick: Whh from resident regs, h via broadcast LDS reads
#define SCANTICK(R, XV, TAU) {                                          \
    float4 xv_ = (XV);                                                  \
    float aI = xv_.x, aF = xv_.y, aG = xv_.z, aO = xv_.w;               \
    _Pragma("unroll")                                                   \
    for (int s = 0; s < 8; s++) {                                       \
        u4v hq = hs[s];                                                 \
        FD4(hq, whh[0 + s],  aI);                                       \
        FD4(hq, whh[8 + s],  aF);                                       \
        FD4(hq, whh[16 + s], aG);                                       \
        FD4(hq, whh[24 + s], aO);                                       \
    }                                                                   \
    cst = sigmoidf_(aF) * cst + sigmoidf_(aI) * tanhf_(aG);             \
    float hv = sigmoidf_(aO) * tanhf_(cst);                             \
    hself[l][u] = (_Float16)hv;                                         \
    if (l < 2) hpub[(R) * 64 + u] = (_Float16)hv;                       \
    else       houtp[(size_t)(TAU) * 64] = hv;                          \
}

    const int NC = T / RR;
    for (int e = 0; e < NC + 2; e++) {
        int m = e - l;
        if (m >= 0 && m < NC) {
            const int p = m & 1;
            const int base = m * RR;
            _Float16* hpub = &hchunk[l < 2 ? l : 0][p][0][0];
            if (l == 0) {
#pragma unroll
                for (int r = 0; r < RR; r++) {
                    int tau = base + r;
                    float4 xv = acc4[r & 3];
                    int tp = tau + 4; if (tp > T - 1) tp = T - 1;
                    acc4[r & 3] = xp[(size_t)tp * 64];
                    SCANTICK(r, xv, tau)
                }
            } else {
                const u4v* hbase = (const u4v*)&hchunk[lb][p][0][0];
                GEMMHALF(0)
                SCANTICK(0, acc4[0], base + 0)
                SCANTICK(1, acc4[1], base + 1)
                SCANTICK(2, acc4[2], base + 2)
                SCANTICK(3, acc4[3], base + 3)
                GEMMHALF(1)
                SCANTICK(4, acc4[0], base + 4)
                SCANTICK(5, acc4[1], base + 5)
                SCANTICK(6, acc4[2], base + 6)
                SCANTICK(7, acc4[3], base + 7)
            }
        }
        LDS_BARRIER();   // publish hchunk writes; epoch parity flip
    }
#undef FD
#undef FD4
#undef GEMMG
#undef GEMMHALF
#undef SCANTICK
}

// ---------------------------------------------------------------------------
// Hc[b, {max,mean,std(ddof=1)}, t] over hidden dim (64). One wave per (b,t).
// ---------------------------------------------------------------------------
__global__ __launch_bounds__(256) void stats_kernel(
    const float* __restrict__ H, float* __restrict__ Hc, int T)
{
    int wid = threadIdx.x >> 6, lane = threadIdx.x & 63;
    int bt = blockIdx.x * 4 + wid;
    int b = bt / T, t = bt - b * T;

    float x = H[(size_t)bt * 64 + lane];
    float mx = x, sm = x;
#pragma unroll
    for (int m = 32; m >= 1; m >>= 1) {
        mx = fmaxf(mx, __shfl_xor(mx, m));
        sm += __shfl_xor(sm, m);
    }
    float mean = sm * (1.0f / 64.0f);
    float d = x - mean;
    float ss = d * d;
#pragma unroll
    for (int m = 32; m >= 1; m >>= 1) ss += __shfl_xor(ss, m);
    float sd = sqrtf(ss * (1.0f / 63.0f));

    if (lane == 0) {
        float* o = Hc + (size_t)b * 3 * T;
        o[0 * T + t] = mx;
        o[1 * T + t] = mean;
        o[2 * T + t] = sd;
    }
}

// ---------------------------------------------------------------------------
// Middle conv/BN chain, single workgroup (1024 threads).
// ---------------------------------------------------------------------------
template <int CIN, int COUT, int MODE>
DEV void conv_bn_stage(const float* __restrict__ in, const float* __restrict__ w,
                       const float* __restrict__ bias, float* __restrict__ out,
                       float* __restrict__ gate, int T, int tid,
                       float* rs, float* rq, float* stm, float* sti)
{
    float lsum[COUT], lss[COUT];
#pragma unroll
    for (int oc = 0; oc < COUT; oc++) { lsum[oc] = 0.f; lss[oc] = 0.f; }

    for (int k = 0; k < 8; k++) {
        int p = tid + k * 1024;
        int b = p / T;
        int t = p - b * T;
        float acc[COUT];
#pragma unroll
        for (int oc = 0; oc < COUT; oc++) acc[oc] = bias[oc];
#pragma unroll
        for (int ic = 0; ic < CIN; ic++) {
            const float* row = in + ((size_t)b * CIN + ic) * T;
            float xv[11];
#pragma unroll
            for (int kk = 0; kk < 11; kk++) {
                int tt = t + kk - 5;
                xv[kk] = (tt >= 0 && tt < T) ? row[tt] : 0.f;
            }
#pragma unroll
            for (int oc = 0; oc < COUT; oc++) {
                const float* wr = w + ((size_t)oc * CIN + ic) * 11;
#pragma unroll
                for (int kk = 0; kk < 11; kk++) acc[oc] += xv[kk] * wr[kk];
            }
        }
#pragma unroll
        for (int oc = 0; oc < COUT; oc++) {
            out[((size_t)b * COUT + oc) * T + t] = acc[oc];
            lsum[oc] += acc[oc];
            lss[oc] += acc[oc] * acc[oc];
        }
    }
    __syncthreads();

    int lane = tid & 63, wid = tid >> 6;
#pragma unroll
    for (int oc = 0; oc < COUT; oc++) {
        float s = lsum[oc], qq = lss[oc];
#pragma unroll
        for (int m = 32; m >= 1; m >>= 1) {
            s += __shfl_xor(s, m);
            qq += __shfl_xor(qq, m);
        }
        if (lane == 0) { rs[wid] = s; rq[wid] = qq; }
        __syncthreads();
        if (tid == 0) {
            float S = 0.f, Q = 0.f;
            for (int i = 0; i < 16; i++) { S += rs[i]; Q += rq[i]; }
            float m_ = S / (float)(2 * T);
            float v = Q / (float)(2 * T) - m_ * m_;
            stm[oc] = m_;
            sti[oc] = rsqrtf(v + 1e-5f);
        }
        __syncthreads();
    }

    for (int k = 0; k < 8; k++) {
        int p = tid + k * 1024;
        int b = p / T;
        int t = p - b * T;
#pragma unroll
        for (int oc = 0; oc < COUT; oc++) {
            size_t idx = ((size_t)b * COUT + oc) * T + t;
            float v = (out[idx] - stm[oc]) * sti[oc];
            if (MODE == 0) out[idx] = fmaxf(v, 0.f);
            else           gate[p] = sigmoidf_(v);
        }
    }
    __syncthreads();
}

__global__ __launch_bounds__(1024) void middle_kernel(
    const float* __restrict__ Hc,
    const float* __restrict__ w1, const float* __restrict__ b1,
    const float* __restrict__ w2, const float* __restrict__ b2,
    const float* __restrict__ w3, const float* __restrict__ b3,
    const float* __restrict__ w4, const float* __restrict__ b4,
    float* __restrict__ bufA, float* __restrict__ bufB,
    float* __restrict__ gate, int T)
{
    __shared__ float rs[16], rq[16], stm[8], sti[8];
    int tid = threadIdx.x;
    conv_bn_stage<3, 3, 0>(Hc,   w1, b1, bufA, nullptr, T, tid, rs, rq, stm, sti);
    conv_bn_stage<3, 5, 0>(bufA, w2, b2, bufB, nullptr, T, tid, rs, rq, stm, sti);
    conv_bn_stage<5, 5, 0>(bufB, w3, b3, bufA, nullptr, T, tid, rs, rq, stm, sti);
    conv_bn_stage<5, 1, 1>(bufA, w4, b4, bufB, gate,    T, tid, rs, rq, stm, sti);
}

// ---------------------------------------------------------------------------
// Head: y = sigmoid(fc2(fc1(out2))). One wave per (b,t).
// ---------------------------------------------------------------------------
__global__ __launch_bounds__(256) void final_kernel(
    const float* __restrict__ out2, const float* __restrict__ fc1w,
    const float* __restrict__ fc1b, const float* __restrict__ fc2w,
    const float* __restrict__ fc2b, float* __restrict__ out, int T)
{
    int wid = threadIdx.x >> 6, lane = threadIdx.x & 63;
    int bt = blockIdx.x * 4 + wid;

    const float* o2 = out2 + (size_t)bt * 64;
    float acc = fc1b[lane];
    const float* wr = fc1w + (size_t)lane * 64;
#pragma unroll
    for (int k = 0; k < 64; k++) acc += o2[k] * wr[k];

    float p = acc * fc2w[lane];
#pragma unroll
    for (int m = 32; m >= 1; m >>= 1) p += __shfl_xor(p, m);

    if (lane == 0) out[bt] = sigmoidf_(p + fc2b[0]);
}

// ---------------------------------------------------------------------------
extern "C" void kernel_launch(void* const* d_in, const int* in_sizes, int n_in,
                              void* d_out, int out_size, void* d_ws, size_t ws_size,
                              hipStream_t stream)
{
    const float* data  = (const float*)d_in[0];
    const float* h01   = (const float*)d_in[1];
    const float* c01   = (const float*)d_in[2];
    const float* h02   = (const float*)d_in[3];
    const float* c02   = (const float*)d_in[4];
    const float* Wih0  = (const float*)d_in[5];
    const float* Wih12 = (const float*)d_in[6];
    const float* l1Whh = (const float*)d_in[7];
    const float* l1b   = (const float*)d_in[8];
    const float* l2Wih = (const float*)d_in[9];
    const float* l2Whh = (const float*)d_in[10];
    const float* l2b   = (const float*)d_in[11];
    const float* cw1 = (const float*)d_in[12]; const float* cb1 = (const float*)d_in[13];
    const float* cw2 = (const float*)d_in[14]; const float* cb2 = (const float*)d_in[15];
    const float* cw3 = (const float*)d_in[16]; const float* cb3 = (const float*)d_in[17];
    const float* cw4 = (const float*)d_in[18]; const float* cb4 = (const float*)d_in[19];
    const float* fc1w = (const float*)d_in[20]; const float* fc1b = (const float*)d_in[21];
    const float* fc2w = (const float*)d_in[22]; const float* fc2b = (const float*)d_in[23];
    float* out = (float*)d_out;

    const int T = in_sizes[0] / (2 * 40);   // 4096
    const int B = 2;

    float* ws   = (float*)d_ws;
    float* xg   = ws;                                // B*T*256
    float* seqA = xg   + (size_t)B * T * 256;        // B*T*64
    float* seqB = seqA + (size_t)B * T * 64;         // B*T*64
    float* Hc   = seqB + (size_t)B * T * 64;         // B*3*T
    float* bufA = Hc   + (size_t)B * 3 * T;          // B*5*T
    float* bufB = bufA + (size_t)B * 5 * T;          // B*5*T
    float* gate = bufB + (size_t)B * 5 * T;          // B*T
    unsigned* wP = (unsigned*)(gate + (size_t)B * T); // 10*8192 u32

    dim3 pg(B * (T / 16)), pb(256);

    pack_w<<<320, 256, 0, stream>>>(l1Whh, l2Whh, Wih12, l2Wih, wP);

    // ---- LSTM1: proj layer0 + chunked 3-layer scan ----
    proj_kernel<<<pg, pb, 0, stream>>>(data, Wih0, l1b, nullptr, xg, 40, T);
    scan3_kernel<<<2, 192, 0, stream>>>(xg, wP, wP + 6 * 8192, l1b, h01, c01, seqA, T);

    // ---- temporal-attention gate ----
    stats_kernel<<<(2 * T) / 4, 256, 0, stream>>>(seqA, Hc, T);
    middle_kernel<<<1, 1024, 0, stream>>>(Hc, cw1, cb1, cw2, cb2, cw3, cb3, cw4, cb4,
                                          bufA, bufB, gate, T);

    // ---- LSTM2: proj layer0 (gate folded) + chunked 3-layer scan ----
    proj_kernel<<<pg, pb, 0, stream>>>(seqA, l2Wih, l2b, gate, xg, 64, T);
    scan3_kernel<<<2, 192, 0, stream>>>(xg, wP + 3 * 8192, wP + 8 * 8192, l2b, h02, c02, seqB, T);

    // ---- head ----
    final_kernel<<<(2 * T) / 4, 256, 0, stream>>>(seqB, fc1w, fc1b, fc2w, fc2b, out, T);
}

// Round 6
// 7970.317 us; speedup vs baseline: 1.8002x; 1.8002x over previous
//
#include <hip/hip_runtime.h>
#include <hip/hip_bf16.h>
#include <cstdint>
#include <cstddef>

#define DEV __device__ __forceinline__

typedef _Float16 h2v __attribute__((ext_vector_type(2)));
typedef _Float16 f16x8 __attribute__((ext_vector_type(8)));
typedef unsigned u4v __attribute__((ext_vector_type(4)));
typedef float f32x4 __attribute__((ext_vector_type(4)));
typedef float f32x2 __attribute__((ext_vector_type(2)));

DEV float sigmoidf_(float x) { return 1.0f / (1.0f + __expf(-x)); }
DEV float tanhf_(float x) {
    float e = __expf(2.0f * x);
    return 1.0f - 2.0f / (e + 1.0f);
}

// Un-sinkable, un-rematerializable 16B load (resident weight fragments).
DEV u4v gload(const void* p) {
    u4v r;
    asm volatile("global_load_dwordx4 %0, %1, off\n\ts_waitcnt vmcnt(0)"
                 : "=v"(r) : "v"(p) : "memory");
    return r;
}

DEV f16x8 asF16(u4v v) { union { u4v u; f16x8 h; } c; c.u = v; return c.h; }

// LDS-only barrier: does NOT drain vmcnt; global stores stay in flight.
#define LDS_BARRIER() asm volatile("s_waitcnt lgkmcnt(0)\n\ts_barrier" ::: "memory")

#define MFMA(A, B, C) __builtin_amdgcn_mfma_f32_16x16x32_f16((A), (B), (C), 0, 0, 0)

// ---------------------------------------------------------------------------
// Pack 10 matrices (256x64 each) into MFMA B-fragments (f16):
//   frag(m, tile t, k-slice s): lane holds B[k = 32s + (lane>>4)*8 + j]
//                                         [n = 16t + (lane&15)],  j = 0..7
//   u32 index within matrix: ((t*2+s)*64 + lane)*4 + jp   (jp = j/2)
// m: 0-2 l1Whh, 3-5 l2Whh, 6-7 l1Wih (layers 1,2), 8-9 l2Wih (layers 1,2).
// B[k][n] = W[n][k] with W row-major [256][64] (rows = gate-unit gu=g*64+u).
// ---------------------------------------------------------------------------
__global__ __launch_bounds__(256) void pack_w(
    const float* __restrict__ l1Whh, const float* __restrict__ l2Whh,
    const float* __restrict__ Wih12, const float* __restrict__ l2Wih,
    unsigned* __restrict__ wP)
{
    int idx = blockIdx.x * 256 + threadIdx.x;   // 10*8192 = 81920
    int m = idx >> 13;
    int w = idx & 8191;
    int t    = w >> 9;
    int s    = (w >> 8) & 1;
    int lane = (w >> 2) & 63;
    int jp   = w & 3;
    int gu = 16 * t + (lane & 15);
    int k  = 32 * s + (lane >> 4) * 8 + 2 * jp;

    const float* W;
    if (m < 3)      W = l1Whh + (size_t)m * 16384;
    else if (m < 6) W = l2Whh + (size_t)(m - 3) * 16384;
    else if (m < 8) W = Wih12 + (size_t)(m - 6) * 16384;
    else            W = l2Wih + (size_t)(m - 7) * 16384;   // layers 1,2

    const float* e = W + (size_t)gu * 64 + k;
    union { h2v h; unsigned u32; } c;
    c.h = (h2v){(_Float16)e[0], (_Float16)e[1]};
    wP[idx] = c.u32;
}

// ---------------------------------------------------------------------------
// Input projection (layer 0 of each stack only): xg[b,t,u*4+g] unit-major.
// ---------------------------------------------------------------------------
__global__ __launch_bounds__(256) void proj_kernel(
    const float* __restrict__ x, const float* __restrict__ Wih,
    const float* __restrict__ bias, const float* __restrict__ gate,
    float* __restrict__ xg, int D, int T)
{
    __shared__ float xS[16 * 64];
    int tb = T / 16;
    int b  = blockIdx.x / tb;
    int t0 = (blockIdx.x % tb) * 16;
    int tid = threadIdx.x;

    int n = 16 * D;
    for (int e = tid; e < n; e += 256) {
        int t = e / D;
        int i = e - t * D;
        float v = x[((size_t)(b * T + t0 + t)) * D + i];
        if (gate) v += gate[b * T + t0 + t];
        xS[t * D + i] = v;
    }
    __syncthreads();

    int g = tid;
    float acc[16];
    float bg = bias[g];
#pragma unroll
    for (int t = 0; t < 16; t++) acc[t] = bg;

    const float* wr = Wih + (size_t)g * D;
    for (int i = 0; i < D; i++) {
        float w = wr[i];
#pragma unroll
        for (int t = 0; t < 16; t++) acc[t] += xS[t * D + i] * w;
    }

    float* og = xg + ((size_t)(b * T + t0)) * 256 + (g & 63) * 4 + (g >> 6);
#pragma unroll
    for (int t = 0; t < 16; t++) og[(size_t)t * 256] = acc[t];
}

// ---------------------------------------------------------------------------
// Chunked 3-layer LSTM scan v21: MFMA matvec. ONE block, THREE waves.
//
// v15-v20 post-mortem: ~8-9 cy per VALU instruction across SIX structures
// and TWO micro-ops (fdot2, fma_mix) -> cannot fix by rearranging VALU.
// v21 cuts instruction count ~6x by moving the matvecs to the matrix pipe:
//  * Both batches ride in one block. Whh per tick: A[16x32] rows 0,1 =
//    h(b0,b1), rows 2-15 zero; B = resident Whh frags (32 = 128 VGPR,
//    cap 512 at 1 wave/SIMD); 16 N-tiles x 2 K-slices = 32 MFMA.
//  * C layout (HW-verified m89): col=lane&15, row=(lane>>4)*4+j ->
//    batches are j=0,1 of lanes 0-15; scatter to paW[u][g][b] (16 b64
//    writes), act phase reads 2 f32x4/lane, 2 cells/lane on 64 lanes.
//  * Wih.h_below per epoch chunk-GEMM: A rows = 8 ticks x 2 batches
//    (M=16 fully used), 32 MFMA/epoch, C scattered to pa2[r][u][g][b].
//  * A/B share the k-slot mapping -> any k-permutation error cancels.
//  * Epochs of RR=8 ticks, 1 barrier/epoch, hchunk parity double-buffer
//    (v18 skeleton). hself/paW/pa2 are same-wave produce->consume.
// ---------------------------------------------------------------------------
#define RR 8

__global__
__attribute__((amdgpu_flat_work_group_size(192, 192), amdgpu_waves_per_eu(1, 1)))
void scan3_kernel(
    const float* __restrict__ xg, const unsigned* __restrict__ whhP,
    const unsigned* __restrict__ wihP, const float* __restrict__ bvec,
    const float* __restrict__ h0, const float* __restrict__ c0,
    float* __restrict__ Hout, int T)
{
    __shared__ __align__(16) _Float16 hself[3][2][64];          // [l][b][u]
    __shared__ __align__(16) _Float16 hchunk[2][2][RR][2][64];  // [par][l][r][b][u]
    __shared__ __align__(16) float paW[3][64][4][2];            // [l][u][g][b]
    __shared__ __align__(16) float pa2[2][RR][64][4][2];        // [l-1][r][u][g][b]

    const int tid = threadIdx.x;
    const int l = tid >> 6, u = tid & 63;
    const int c16 = u & 15, kb = (u >> 4) * 8;

    // ---- resident B-fragments (gload: forced residency) ----
    u4v whhB[32], wihB[32];
    {
        const u4v* wp = (const u4v*)whhP + (size_t)l * 2048;
#pragma unroll
        for (int i = 0; i < 32; i++) whhB[i] = gload(wp + i * 64 + u);
    }
    u4v zq = {0u, 0u, 0u, 0u};
#pragma unroll
    for (int i = 0; i < 32; i++) wihB[i] = zq;
    if (l > 0) {
        const u4v* wp = (const u4v*)wihP + (size_t)(l - 1) * 2048;
#pragma unroll
        for (int i = 0; i < 32; i++) wihB[i] = gload(wp + i * 64 + u);
    }

    // ---- recurrent state (lane = unit, both batches) ----
    float cs0 = c0[l * 128 + u];
    float cs1 = c0[l * 128 + 64 + u];
    hself[l][0][u] = (_Float16)h0[l * 128 + u];
    hself[l][1][u] = (_Float16)h0[l * 128 + 64 + u];
    f32x4 bl = {0.f, 0.f, 0.f, 0.f};
    if (l > 0) {
        const float* bb = bvec + l * 256;
        bl = (f32x4){bb[u], bb[64 + u], bb[128 + u], bb[192 + u]};
    }

    // ---- L0 rolling x prefetch, both batches (gates i,f,g,o per f32x4) ----
    const f32x4* xp0 = (const f32x4*)xg + u;
    const f32x4* xp1 = (const f32x4*)xg + (size_t)T * 64 + u;
    f32x4 xa0[4], xa1[4];
    if (l == 0) {
#pragma unroll
        for (int k = 0; k < 4; k++) { xa0[k] = xp0[(size_t)k * 64]; xa1[k] = xp1[(size_t)k * 64]; }
    }
    float* ho0 = Hout + u;
    float* ho1 = Hout + (size_t)T * 64 + u;

    __syncthreads();

    const int NC = T / RR;
    const f32x4 z4 = {0.f, 0.f, 0.f, 0.f};

    for (int e = 0; e < NC + 2; e++) {
        int m = e - l;
        if (m >= 0 && m < NC) {
            const int p = m & 1;
            const int base = m * RR;

            if (l > 0) {
                // ---- epoch-head chunk GEMM: Wih @ h_below(8 ticks x 2b) ----
                int rr = c16 >> 1, bb2 = c16 & 1;
                f16x8 a0 = *(const f16x8*)&hchunk[p][l - 1][rr][bb2][kb];
                f16x8 a1 = *(const f16x8*)&hchunk[p][l - 1][rr][bb2][32 + kb];
                f32x4 ax[16];
#pragma unroll
                for (int t = 0; t < 16; t++) {
                    ax[t] = MFMA(a0, asF16(wihB[2 * t]), z4);
                    ax[t] = MFMA(a1, asF16(wihB[2 * t + 1]), ax[t]);
                }
                // scatter C rows (j -> tick/batch) to pa2[l-1][r][u][g][b]
                int r0 = (u >> 4) * 2;
#pragma unroll
                for (int t = 0; t < 16; t++) {
                    int gu = 16 * t + c16, g = gu >> 6, uu = gu & 63;
                    *(f32x2*)&pa2[l - 1][r0][uu][g][0]     = (f32x2){ax[t][0], ax[t][1]};
                    *(f32x2*)&pa2[l - 1][r0 + 1][uu][g][0] = (f32x2){ax[t][2], ax[t][3]};
                }
            }

            // ---- 8 ticks ----
#pragma unroll
            for (int r = 0; r < RR; r++) {
                int tau = base + r;
                // A-frags from own hself (rows 0,1 = batches; 2-15 zero)
                f16x8 a0, a1;
                if (c16 < 2) {
                    a0 = *(const f16x8*)&hself[l][c16][kb];
                    a1 = *(const f16x8*)&hself[l][c16][32 + kb];
                } else { a0 = asF16(zq); a1 = asF16(zq); }

                f32x4 aw[16];
#pragma unroll
                for (int t = 0; t < 16; t++) {
                    aw[t] = MFMA(a0, asF16(whhB[2 * t]), z4);
                    aw[t] = MFMA(a1, asF16(whhB[2 * t + 1]), aw[t]);
                }
                // publish preacts: lanes 0-15 hold rows 0,1 (j=0,1)
                if (u < 16) {
#pragma unroll
                    for (int t = 0; t < 16; t++) {
                        int gu = 16 * t + u, g = gu >> 6, uu = gu & 63;
                        *(f32x2*)&paW[l][uu][g][0] = (f32x2){aw[t][0], aw[t][1]};
                    }
                }

                // gather this unit's 4 gates x 2 batches
                f32x4 q0 = *(const f32x4*)&paW[l][u][0][0];  // g0b0 g0b1 g1b0 g1b1
                f32x4 q1 = *(const f32x4*)&paW[l][u][2][0];  // g2b0 g2b1 g3b0 g3b1
                f32x4 xq0, xq1;
                if (l == 0) {
                    xq0 = xa0[r & 3];
                    xq1 = xa1[r & 3];
                    int tp = tau + 4; if (tp > T - 1) tp = T - 1;
                    xa0[r & 3] = xp0[(size_t)tp * 64];
                    xa1[r & 3] = xp1[(size_t)tp * 64];
                } else {
                    f32x4 p0 = *(const f32x4*)&pa2[l - 1][r][u][0][0];
                    f32x4 p1 = *(const f32x4*)&pa2[l - 1][r][u][2][0];
                    xq0 = (f32x4){p0[0] + bl[0], p0[2] + bl[1], p1[0] + bl[2], p1[2] + bl[3]};
                    xq1 = (f32x4){p0[1] + bl[0], p0[3] + bl[1], p1[1] + bl[2], p1[3] + bl[3]};
                }
                float I0 = q0[0] + xq0[0], F0 = q0[2] + xq0[1];
                float G0 = q1[0] + xq0[2], O0 = q1[2] + xq0[3];
                float I1 = q0[1] + xq1[0], F1 = q0[3] + xq1[1];
                float G1 = q1[1] + xq1[2], O1 = q1[3] + xq1[3];

                cs0 = sigmoidf_(F0) * cs0 + sigmoidf_(I0) * tanhf_(G0);
                float h0v = sigmoidf_(O0) * tanhf_(cs0);
                cs1 = sigmoidf_(F1) * cs1 + sigmoidf_(I1) * tanhf_(G1);
                float h1v = sigmoidf_(O1) * tanhf_(cs1);

                hself[l][0][u] = (_Float16)h0v;
                hself[l][1][u] = (_Float16)h1v;
                if (l < 2) {
                    hchunk[p][l][r][0][u] = (_Float16)h0v;
                    hchunk[p][l][r][1][u] = (_Float16)h1v;
                } else {
                    ho0[(size_t)tau * 64] = h0v;
                    ho1[(size_t)tau * 64] = h1v;
                }
            }
        }
        LDS_BARRIER();   // publish hchunk writes; epoch parity flip
    }
}

// ---------------------------------------------------------------------------
// Hc[b, {max,mean,std(ddof=1)}, t] over hidden dim (64). One wave per (b,t).
// ---------------------------------------------------------------------------
__global__ __launch_bounds__(256) void stats_kernel(
    const float* __restrict__ H, float* __restrict__ Hc, int T)
{
    int wid = threadIdx.x >> 6, lane = threadIdx.x & 63;
    int bt = blockIdx.x * 4 + wid;
    int b = bt / T, t = bt - b * T;

    float x = H[(size_t)bt * 64 + lane];
    float mx = x, sm = x;
#pragma unroll
    for (int m = 32; m >= 1; m >>= 1) {
        mx = fmaxf(mx, __shfl_xor(mx, m));
        sm += __shfl_xor(sm, m);
    }
    float mean = sm * (1.0f / 64.0f);
    float d = x - mean;
    float ss = d * d;
#pragma unroll
    for (int m = 32; m >= 1; m >>= 1) ss += __shfl_xor(ss, m);
    float sd = sqrtf(ss * (1.0f / 63.0f));

    if (lane == 0) {
        float* o = Hc + (size_t)b * 3 * T;
        o[0 * T + t] = mx;
        o[1 * T + t] = mean;
        o[2 * T + t] = sd;
    }
}

// ---------------------------------------------------------------------------
// Middle conv/BN chain, single workgroup (1024 threads).
// ---------------------------------------------------------------------------
template <int CIN, int COUT, int MODE>
DEV void conv_bn_stage(const float* __restrict__ in, const float* __restrict__ w,
                       const float* __restrict__ bias, float* __restrict__ out,
                       float* __restrict__ gate, int T, int tid,
                       float* rs, float* rq, float* stm, float* sti)
{
    float lsum[COUT], lss[COUT];
#pragma unroll
    for (int oc = 0; oc < COUT; oc++) { lsum[oc] = 0.f; lss[oc] = 0.f; }

    for (int k = 0; k < 8; k++) {
        int p = tid + k * 1024;
        int b = p / T;
        int t = p - b * T;
        float acc[COUT];
#pragma unroll
        for (int oc = 0; oc < COUT; oc++) acc[oc] = bias[oc];
#pragma unroll
        for (int ic = 0; ic < CIN; ic++) {
            const float* row = in + ((size_t)b * CIN + ic) * T;
            float xv[11];
#pragma unroll
            for (int kk = 0; kk < 11; kk++) {
                int tt = t + kk - 5;
                xv[kk] = (tt >= 0 && tt < T) ? row[tt] : 0.f;
            }
#pragma unroll
            for (int oc = 0; oc < COUT; oc++) {
                const float* wr = w + ((size_t)oc * CIN + ic) * 11;
#pragma unroll
                for (int kk = 0; kk < 11; kk++) acc[oc] += xv[kk] * wr[kk];
            }
        }
#pragma unroll
        for (int oc = 0; oc < COUT; oc++) {
            out[((size_t)b * COUT + oc) * T + t] = acc[oc];
            lsum[oc] += acc[oc];
            lss[oc] += acc[oc] * acc[oc];
        }
    }
    __syncthreads();

    int lane = tid & 63, wid = tid >> 6;
#pragma unroll
    for (int oc = 0; oc < COUT; oc++) {
        float s = lsum[oc], qq = lss[oc];
#pragma unroll
        for (int m = 32; m >= 1; m >>= 1) {
            s += __shfl_xor(s, m);
            qq += __shfl_xor(qq, m);
        }
        if (lane == 0) { rs[wid] = s; rq[wid] = qq; }
        __syncthreads();
        if (tid == 0) {
            float S = 0.f, Q = 0.f;
            for (int i = 0; i < 16; i++) { S += rs[i]; Q += rq[i]; }
            float m_ = S / (float)(2 * T);
            float v = Q / (float)(2 * T) - m_ * m_;
            stm[oc] = m_;
            sti[oc] = rsqrtf(v + 1e-5f);
        }
        __syncthreads();
    }

    for (int k = 0; k < 8; k++) {
        int p = tid + k * 1024;
        int b = p / T;
        int t = p - b * T;
#pragma unroll
        for (int oc = 0; oc < COUT; oc++) {
            size_t idx = ((size_t)b * COUT + oc) * T + t;
            float v = (out[idx] - stm[oc]) * sti[oc];
            if (MODE == 0) out[idx] = fmaxf(v, 0.f);
            else           gate[p] = sigmoidf_(v);
        }
    }
    __syncthreads();
}

__global__ __launch_bounds__(1024) void middle_kernel(
    const float* __restrict__ Hc,
    const float* __restrict__ w1, const float* __restrict__ b1,
    const float* __restrict__ w2, const float* __restrict__ b2,
    const float* __restrict__ w3, const float* __restrict__ b3,
    const float* __restrict__ w4, const float* __restrict__ b4,
    float* __restrict__ bufA, float* __restrict__ bufB,
    float* __restrict__ gate, int T)
{
    __shared__ float rs[16], rq[16], stm[8], sti[8];
    int tid = threadIdx.x;
    conv_bn_stage<3, 3, 0>(Hc,   w1, b1, bufA, nullptr, T, tid, rs, rq, stm, sti);
    conv_bn_stage<3, 5, 0>(bufA, w2, b2, bufB, nullptr, T, tid, rs, rq, stm, sti);
    conv_bn_stage<5, 5, 0>(bufB, w3, b3, bufA, nullptr, T, tid, rs, rq, stm, sti);
    conv_bn_stage<5, 1, 1>(bufA, w4, b4, bufB, gate,    T, tid, rs, rq, stm, sti);
}

// ---------------------------------------------------------------------------
// Head: y = sigmoid(fc2(fc1(out2))). One wave per (b,t).
// ---------------------------------------------------------------------------
__global__ __launch_bounds__(256) void final_kernel(
    const float* __restrict__ out2, const float* __restrict__ fc1w,
    const float* __restrict__ fc1b, const float* __restrict__ fc2w,
    const float* __restrict__ fc2b, float* __restrict__ out, int T)
{
    int wid = threadIdx.x >> 6, lane = threadIdx.x & 63;
    int bt = blockIdx.x * 4 + wid;

    const float* o2 = out2 + (size_t)bt * 64;
    float acc = fc1b[lane];
    const float* wr = fc1w + (size_t)lane * 64;
#pragma unroll
    for (int k = 0; k < 64; k++) acc += o2[k] * wr[k];

    float p = acc * fc2w[lane];
#pragma unroll
    for (int m = 32; m >= 1; m >>= 1) p += __shfl_xor(p, m);

    if (lane == 0) out[bt] = sigmoidf_(p + fc2b[0]);
}

// ---------------------------------------------------------------------------
extern "C" void kernel_launch(void* const* d_in, const int* in_sizes, int n_in,
                              void* d_out, int out_size, void* d_ws, size_t ws_size,
                              hipStream_t stream)
{
    const float* data  = (const float*)d_in[0];
    const float* h01   = (const float*)d_in[1];
    const float* c01   = (const float*)d_in[2];
    const float* h02   = (const float*)d_in[3];
    const float* c02   = (const float*)d_in[4];
    const float* Wih0  = (const float*)d_in[5];
    const float* Wih12 = (const float*)d_in[6];
    const float* l1Whh = (const float*)d_in[7];
    const float* l1b   = (const float*)d_in[8];
    const float* l2Wih = (const float*)d_in[9];
    const float* l2Whh = (const float*)d_in[10];
    const float* l2b   = (const float*)d_in[11];
    const float* cw1 = (const float*)d_in[12]; const float* cb1 = (const float*)d_in[13];
    const float* cw2 = (const float*)d_in[14]; const float* cb2 = (const float*)d_in[15];
    const float* cw3 = (const float*)d_in[16]; const float* cb3 = (const float*)d_in[17];
    const float* cw4 = (const float*)d_in[18]; const float* cb4 = (const float*)d_in[19];
    const float* fc1w = (const float*)d_in[20]; const float* fc1b = (const float*)d_in[21];
    const float* fc2w = (const float*)d_in[22]; const float* fc2b = (const float*)d_in[23];
    float* out = (float*)d_out;

    const int T = in_sizes[0] / (2 * 40);   // 4096
    const int B = 2;

    float* ws   = (float*)d_ws;
    float* xg   = ws;                                // B*T*256
    float* seqA = xg   + (size_t)B * T * 256;        // B*T*64
    float* seqB = seqA + (size_t)B * T * 64;         // B*T*64
    float* Hc   = seqB + (size_t)B * T * 64;         // B*3*T
    float* bufA = Hc   + (size_t)B * 3 * T;          // B*5*T
    float* bufB = bufA + (size_t)B * 5 * T;          // B*5*T
    float* gate = bufB + (size_t)B * 5 * T;          // B*T
    unsigned* wP = (unsigned*)(gate + (size_t)B * T); // 10*8192 u32

    dim3 pg(B * (T / 16)), pb(256);

    pack_w<<<320, 256, 0, stream>>>(l1Whh, l2Whh, Wih12, l2Wih, wP);

    // ---- LSTM1: proj layer0 + MFMA 3-layer scan (both batches, 1 block) ----
    proj_kernel<<<pg, pb, 0, stream>>>(data, Wih0, l1b, nullptr, xg, 40, T);
    scan3_kernel<<<1, 192, 0, stream>>>(xg, wP, wP + 6 * 8192, l1b, h01, c01, seqA, T);

    // ---- temporal-attention gate ----
    stats_kernel<<<(2 * T) / 4, 256, 0, stream>>>(seqA, Hc, T);
    middle_kernel<<<1, 1024, 0, stream>>>(Hc, cw1, cb1, cw2, cb2, cw3, cb3, cw4, cb4,
                                          bufA, bufB, gate, T);

    // ---- LSTM2: proj layer0 (gate folded) + MFMA 3-layer scan ----
    proj_kernel<<<pg, pb, 0, stream>>>(seqA, l2Wih, l2b, gate, xg, 64, T);
    scan3_kernel<<<1, 192, 0, stream>>>(xg, wP + 3 * 8192, wP + 8 * 8192, l2b, h02, c02, seqB, T);

    // ---- head ----
    final_kernel<<<(2 * T) / 4, 256, 0, stream>>>(seqB, fc1w, fc1b, fc2w, fc2b, out, T);
}